// Round 20
// baseline (183.144 us; speedup 1.0000x reference)
//
#include <hip/hip_runtime.h>
#include <hip/hip_bf16.h>
#include <math.h>

// ---------------- problem constants ----------------
#define D_MODEL 768
#define D_STATE 16
#define DT_RANK 48
#define D_INNER 1536           // 2*D_MODEL
#define XZ_DIM  3072           // 2*D_INNER
#define PROJ_DIM 80            // DT_RANK + 2*D_STATE
#define Bb 2
#define Ll 1024
#define ROWS (Bb*Ll)           // 2048

// ---------------- ws layout (float offsets; bf16 buffers reuse same regions) ----------------
#define OFF_PART   0u                     // (legacy, unused)
#define OFF_SW     256u                   // 4 scalars
#define OFF_WQIN   512u                   // bf16 [3072][768]
#define OFF_WQXPT  (OFF_WQIN  + 2359296u) // f32 [1536][80] (transposed)
#define OFF_WQDT   (OFF_WQXPT + 122880u)  // bf16 [1536][64] (K zero-padded 48->64)
#define OFF_WQOUT  (OFF_WQDT  + 73728u)   // bf16 [768][1536]
#define OFF_XQ1    (OFF_WQOUT + 1179648u) // bf16 [2048][768]
#define OFF_S1     (OFF_XQ1   + 1572864u) // 2048
#define OFF_XZ     (OFF_S1    + 2048u)    // f32 [2048][3072]
#define OFF_XS     (OFF_XZ    + 6291456u) // f32 [2048][1536]
#define OFF_YG     (OFF_XS    + 3145728u) // f32 [2048][1536] (raw y, pre-gate)
#define OFF_S2     (OFF_YG    + 3145728u) // 2048 floats -> absmean partials (1024 used)
#define OFF_PROJ   (OFF_S2    + 2048u)    // f32 [2048][80]
#define OFF_XQ3    (OFF_PROJ  + 163840u)  // bf16 [2048][64] (padded)
#define OFF_S3     (OFF_XQ3   + 98304u)   // 2048
#define OFF_DMX    (OFF_S3    + 2048u)    // float2 [1536*2][1024] = 6291456 floats
#define OFF_XQ4    (OFF_DMX   + 6291456u) // bf16 [2048][1536]
#define OFF_S4     (OFF_XQ4   + 3145728u) // 2048

typedef short sh8 __attribute__((ext_vector_type(8)));
typedef float f32x4 __attribute__((ext_vector_type(4)));

#define N_IN_W  (XZ_DIM * D_MODEL)     // 2359296
#define N_XP_W  (PROJ_DIM * D_INNER)   // 122880
#define N_DT_P  (D_INNER * 64)         // 98304 (padded)
#define N_OUT_W (D_MODEL * D_INNER)    // 1179648

// ---------------- helpers ----------------
__device__ __forceinline__ float blk_sum(float v, float* sm) {
    int tid = threadIdx.x;
    #pragma unroll
    for (int off = 32; off; off >>= 1) v += __shfl_down(v, off);
    __syncthreads();
    if ((tid & 63) == 0) sm[tid >> 6] = v;
    __syncthreads();
    return (sm[0] + sm[1]) + (sm[2] + sm[3]);
}
__device__ __forceinline__ float blk_max(float v, float* sm) {
    int tid = threadIdx.x;
    #pragma unroll
    for (int off = 32; off; off >>= 1) v = fmaxf(v, __shfl_down(v, off));
    __syncthreads();
    if ((tid & 63) == 0) sm[tid >> 6] = v;
    __syncthreads();
    return fmaxf(fmaxf(sm[0], sm[1]), fmaxf(sm[2], sm[3]));
}
__device__ __forceinline__ float clampf(float v, float lo, float hi) {
    return fminf(fmaxf(v, lo), hi);
}
__device__ __forceinline__ void gload_lds16(const __hip_bfloat16* g, __hip_bfloat16* l) {
    __builtin_amdgcn_global_load_lds(
        (const __attribute__((address_space(1))) void*)g,
        (__attribute__((address_space(3))) void*)l, 16, 0, 0);
}

// ---------------- weight absmean: 1024 partial blocks (full occupancy) ----------------
__global__ __launch_bounds__(256) void absmean_all(
    const float* __restrict__ w0, const float* __restrict__ w1,
    const float* __restrict__ w2, const float* __restrict__ w3,
    float* __restrict__ part) {
    __shared__ float sm[4];
    int bid = blockIdx.x;
    const float* w; int n, sub, nb;
    if (bid < 512)      { w = w0; n = N_IN_W;           sub = bid;       nb = 512; }
    else if (bid < 576) { w = w1; n = N_XP_W;           sub = bid - 512; nb = 64;  }
    else if (bid < 640) { w = w2; n = D_INNER*DT_RANK;  sub = bid - 576; nb = 64;  }
    else                { w = w3; n = N_OUT_W;          sub = bid - 640; nb = 384; }
    float sum = 0.f;
    for (int i = sub * 256 + threadIdx.x; i < n; i += nb * 256)
        sum += fabsf(w[i]);
    sum = blk_sum(sum, sm);
    if (threadIdx.x == 0) part[bid] = sum;
}

__global__ __launch_bounds__(256) void absmean_final4(
    const float* __restrict__ part, float* __restrict__ sw) {
    __shared__ float sm[4];
    int tid = threadIdx.x;  // 256 threads
    const int cnt[4] = {512, 64, 64, 384};
    const int off[4] = {0, 512, 576, 640};
    const int ns[4]  = {N_IN_W, N_XP_W, D_INNER*DT_RANK, N_OUT_W};
    #pragma unroll
    for (int m = 0; m < 4; ++m) {
        float v = 0.f;
        for (int i = tid; i < cnt[m]; i += 256) v += part[off[m] + i];
        v = blk_sum(v, sm);
        if (tid == 0) sw[m] = v / (float)ns[m] + 1e-6f;
    }
}

// ---------------- all 4 weight quantizations in one launch ----------------
__global__ void quant_all(const float* __restrict__ w_in, const float* __restrict__ w_xp,
                          const float* __restrict__ w_dt, const float* __restrict__ w_out,
                          const float* __restrict__ sw,
                          __hip_bfloat16* __restrict__ wqin, float* __restrict__ wqxpT,
                          __hip_bfloat16* __restrict__ wqdt, __hip_bfloat16* __restrict__ wqout) {
    int idx = blockIdx.x * 256 + threadIdx.x;
    if (idx < N_IN_W) {
        float v = rintf(clampf(w_in[idx] / sw[0], -1.f, 1.f));
        wqin[idx] = __float2bfloat16(v);
    } else if (idx < N_IN_W + N_XP_W) {
        int i = idx - N_IN_W;
        int j = i / D_INNER, k = i % D_INNER;
        wqxpT[k * PROJ_DIM + j] = rintf(clampf(w_xp[i] / sw[1], -1.f, 1.f));
    } else if (idx < N_IN_W + N_XP_W + N_DT_P) {
        int i = idx - N_IN_W - N_XP_W;
        int r = i >> 6, c = i & 63;
        float v = (c < DT_RANK) ? rintf(clampf(w_dt[r * DT_RANK + c] / sw[2], -1.f, 1.f)) : 0.f;
        wqdt[i] = __float2bfloat16(v);
    } else if (idx < N_IN_W + N_XP_W + N_DT_P + N_OUT_W) {
        int i = idx - N_IN_W - N_XP_W - N_DT_P;
        float v = rintf(clampf(w_out[i] / sw[3], -1.f, 1.f));
        wqout[i] = __float2bfloat16(v);
    }
}

// ---------------- fused center x2 + bitshift-norm + act quant (bf16 out) ----------------
__global__ __launch_bounds__(256) void norm_quant(
    const float* __restrict__ x, const float* __restrict__ gamma,
    const float* __restrict__ swp, __hip_bfloat16* __restrict__ xq, float* __restrict__ s1) {
    int row = blockIdx.x, tid = threadIdx.x;
    const float* xr = x + (size_t)row * D_MODEL;
    __shared__ float sm[4];
    float v0 = xr[tid], v1 = xr[tid + 256], v2 = xr[tid + 512];
    float m1 = blk_sum(v0 + v1 + v2, sm) * (1.f / D_MODEL);
    v0 -= m1; v1 -= m1; v2 -= m1;
    float m2 = blk_sum(v0 + v1 + v2, sm) * (1.f / D_MODEL);
    v0 -= m2; v1 -= m2; v2 -= m2;
    float var = blk_sum(v0 * v0 + v1 * v1 + v2 * v2, sm) * (1.f / D_MODEL);
    float rms = sqrtf(var + 1e-6f);
    float k = fmaxf(rintf(log2f(rms)), 0.f);
    float inv = exp2f(-k);
    float g0 = gamma[tid], g1 = gamma[tid + 256], g2 = gamma[tid + 512];
    float h0 = v0 * inv * g0, h1 = v1 * inv * g1, h2 = v2 * inv * g2;
    float mx = blk_max(fmaxf(fabsf(h0), fmaxf(fabsf(h1), fabsf(h2))), sm);
    float sx = 127.f / (mx + 1e-6f);
    __hip_bfloat16* xo = xq + (size_t)row * D_MODEL;
    xo[tid]       = __float2bfloat16(rintf(clampf(h0 * sx, -128.f, 127.f)));
    xo[tid + 256] = __float2bfloat16(rintf(clampf(h1 * sx, -128.f, 127.f)));
    xo[tid + 512] = __float2bfloat16(rintf(clampf(h2 * sx, -128.f, 127.f)));
    if (tid == 0) s1[row] = swp[0] * (mx + 1e-6f) / 127.f;
}

// ---------------- gate + row-wise |max| + act quant (bf16 out) ----------------
__global__ __launch_bounds__(256) void gate_rowmax_quant_bf16(
    const float* __restrict__ yr, const float* __restrict__ xz,
    const float* __restrict__ swp,
    __hip_bfloat16* __restrict__ xq, float* __restrict__ sout) {
    int row = blockIdx.x, tid = threadIdx.x;
    const float* ir = yr + (size_t)row * D_INNER;
    const float* zr = xz + (size_t)row * XZ_DIM + D_INNER;
    __shared__ float sm[4];
    float v[6];
    #pragma unroll
    for (int k6 = 0; k6 < 6; ++k6) {
        int k = tid + k6 * 256;
        float z = zr[k];
        float g = 0.5f * (z / sqrtf(fmaf(z, z, 1.f)) + 1.f);
        v[k6] = ir[k] * g;
    }
    float mx = 0.f;
    #pragma unroll
    for (int k6 = 0; k6 < 6; ++k6) mx = fmaxf(mx, fabsf(v[k6]));
    mx = blk_max(mx, sm);
    float sx = 127.f / (mx + 1e-6f);
    #pragma unroll
    for (int k6 = 0; k6 < 6; ++k6) {
        int k = tid + k6 * 256;
        xq[(size_t)row * D_INNER + k] = __float2bfloat16(rintf(clampf(v[k6] * sx, -128.f, 127.f)));
    }
    if (tid == 0) sout[row] = swp[0] * (mx + 1e-6f) / 127.f;
}

// ---------------- MFMA bf16 GEMM: C[M,N] = (A[M,K] @ W[N,K]^T) * s[row] (+resid) ----------------
template<int MF, int NF>
__global__ __launch_bounds__(256) void gemm_mfma(
    const __hip_bfloat16* __restrict__ A, const __hip_bfloat16* __restrict__ W,
    const float* __restrict__ s, float* __restrict__ C,
    int M, int N, int K,
    const float* __restrict__ resid, const float* __restrict__ rg) {
    constexpr int BM = MF * 32, BN = NF * 32;
    __shared__ __hip_bfloat16 smA[BM * 32];
    __shared__ __hip_bfloat16 smB[BN * 32];
    const int tid = threadIdx.x;
    const int w = tid >> 6, lane = tid & 63;
    const int bm = blockIdx.y * BM, bn = blockIdx.x * BN;
    const int wr = (w >> 1) * (MF * 16), wc = (w & 1) * (NF * 16);
    const int fr = lane & 15, fq = lane >> 4;
    const int srow = lane >> 2;
    const int scol = (lane & 3) * 8;

    f32x4 acc[MF][NF];
    #pragma unroll
    for (int i = 0; i < MF; ++i)
        #pragma unroll
        for (int j = 0; j < NF; ++j)
            acc[i][j] = (f32x4){0.f, 0.f, 0.f, 0.f};

    for (int k0 = 0; k0 < K; k0 += 32) {
        #pragma unroll
        for (int q = 0; q < BM / 64; ++q) {
            int rr = (w * (BM / 64) + q) * 16;
            gload_lds16(A + (size_t)(bm + rr + srow) * K + k0 + scol, &smA[rr * 32]);
        }
        if (w < (BN / 16)) {
            int rr = w * 16;
            gload_lds16(W + (size_t)(bn + rr + srow) * K + k0 + scol, &smB[rr * 32]);
        }
        __syncthreads();
        sh8 af[MF], bfr[NF];
        #pragma unroll
        for (int i = 0; i < MF; ++i)
            af[i] = *(const sh8*)&smA[(wr + i * 16 + fr) * 32 + fq * 8];
        #pragma unroll
        for (int j = 0; j < NF; ++j)
            bfr[j] = *(const sh8*)&smB[(wc + j * 16 + fr) * 32 + fq * 8];
        #pragma unroll
        for (int i = 0; i < MF; ++i)
            #pragma unroll
            for (int j = 0; j < NF; ++j)
                acc[i][j] = __builtin_amdgcn_mfma_f32_16x16x32_bf16(af[i], bfr[j], acc[i][j], 0, 0, 0);
        __syncthreads();
    }
    const float rgv = resid ? rg[0] : 0.f;
    #pragma unroll
    for (int i = 0; i < MF; ++i) {
        #pragma unroll
        for (int q = 0; q < 4; ++q) {
            int r = bm + wr + i * 16 + fq * 4 + q;
            float sc = s[r];
            #pragma unroll
            for (int j = 0; j < NF; ++j) {
                int col = bn + wc + j * 16 + fr;
                float v = acc[i][j][q] * sc;
                size_t o = (size_t)r * N + col;
                if (resid) v = resid[o] + v * rgv;
                C[o] = v;
            }
        }
    }
}

// ---------------- FUSED (2 rows/block): conv+softplus+quant(LDS) + x_proj GEMM + dt-quant ----------------
#define CR2 2
__global__ __launch_bounds__(512) void conv_xproj(
    const float* __restrict__ xz, const float* __restrict__ cw, const float* __restrict__ cb,
    const float* __restrict__ swp,            // sw[4]; uses [1] for x_proj, [2] for dt
    const float* __restrict__ wT,             // wqxpT f32 [1536][80]
    float* __restrict__ xs,
    float* __restrict__ proj, __hip_bfloat16* __restrict__ xq3, float* __restrict__ s3) {
    int row0 = blockIdx.x * CR2;
    int tid = threadIdx.x;
    int w = tid >> 6, lane = tid & 63;
    int r = w >> 2, q = w & 3;
    __shared__ float sm8[8];
    __shared__ float a[CR2][D_INNER];           // 12.3 KB
    __shared__ float psum[16][CR2][PROJ_DIM];   // 10.2 KB
    __shared__ float pvL[CR2][PROJ_DIM];        // 0.6 KB
    __shared__ float s2s[CR2];

    // phase 1: conv + softplus (4 waves per row, 384 channels each)
    int row = row0 + r;
    int b = row >> 10, l = row & 1023;
    float v[6];
    float mx = 0.f;
    #pragma unroll
    for (int k = 0; k < 6; ++k) {
        int c = q * 384 + lane + k * 64;
        float acc = cb[c];
        #pragma unroll
        for (int t = 0; t < 4; ++t) {
            int tt = l - 3 + t;
            if (tt >= 0)
                acc = fmaf(cw[c * 4 + t], xz[(size_t)(b * Ll + tt) * XZ_DIM + c], acc);
        }
        acc = clampf(acc, -50.f, 50.f);
        v[k] = 0.5f * (acc + sqrtf(fmaf(acc, acc, 4.f)));
        mx = fmaxf(mx, fabsf(v[k]));
    }
    #pragma unroll
    for (int off = 32; off; off >>= 1) mx = fmaxf(mx, __shfl_xor(mx, off));
    if (lane == 0) sm8[w] = mx;
    __syncthreads();
    mx = fmaxf(fmaxf(sm8[r * 4 + 0], sm8[r * 4 + 1]), fmaxf(sm8[r * 4 + 2], sm8[r * 4 + 3]));
    float sx = 127.f / (mx + 1e-6f);
    #pragma unroll
    for (int k = 0; k < 6; ++k) {
        int c = q * 384 + lane + k * 64;
        xs[(size_t)row * D_INNER + c] = v[k];
        a[r][c] = rintf(clampf(v[k] * sx, -128.f, 127.f));
    }
    if (lane == 0 && q == 0) s2s[r] = swp[1] * (mx + 1e-6f) / 127.f;
    __syncthreads();

    // phase 2: 1280 tasks = 16 K-chunks x 80 cols; both rows per wT load
    for (int task = tid; task < 16 * PROJ_DIM; task += 512) {
        int h = task / PROJ_DIM;
        int col = task - h * PROJ_DIM;
        int k0 = h * 96;
        float a0 = 0.f, a1 = 0.f;
        for (int k = k0; k < k0 + 96; ++k) {
            float wv = wT[k * PROJ_DIM + col];
            a0 = fmaf(a[0][k], wv, a0);
            a1 = fmaf(a[1][k], wv, a1);
        }
        psum[h][0][col] = a0;
        psum[h][1][col] = a1;
    }
    __syncthreads();
    for (int o = tid; o < CR2 * PROJ_DIM; o += 512) {
        int rr = o / PROJ_DIM, col = o - rr * PROJ_DIM;
        float p0 = (psum[0][rr][col] + psum[1][rr][col]) + (psum[2][rr][col] + psum[3][rr][col]);
        float p1 = (psum[4][rr][col] + psum[5][rr][col]) + (psum[6][rr][col] + psum[7][rr][col]);
        float p2 = (psum[8][rr][col] + psum[9][rr][col]) + (psum[10][rr][col] + psum[11][rr][col]);
        float p3 = (psum[12][rr][col] + psum[13][rr][col]) + (psum[14][rr][col] + psum[15][rr][col]);
        float pv = ((p0 + p1) + (p2 + p3)) * s2s[rr];
        proj[(size_t)(row0 + rr) * PROJ_DIM + col] = pv;
        pvL[rr][col] = pv;
    }
    __syncthreads();
    // dt-quant: waves 0..1 handle rows 0..1
    if (w < CR2) {
        float pvv = (lane < DT_RANK) ? pvL[w][lane] : 0.f;
        float av = fabsf(pvv);
        #pragma unroll
        for (int off = 32; off; off >>= 1) av = fmaxf(av, __shfl_xor(av, off));
        float sxd = 127.f / (av + 1e-6f);
        float qv = (lane < DT_RANK) ? rintf(clampf(pvv * sxd, -128.f, 127.f)) : 0.f;
        xq3[(size_t)(row0 + w) * 64 + lane] = __float2bfloat16(qv);
        if (lane == 0) s3[row0 + w] = swp[2] * (av + 1e-6f) / 127.f;
    }
}

// ---------------- dt_proj MFMA GEMM (K=64 padded) + fused dtv/xdt + transpose -> float2 dmx ----------------
__global__ __launch_bounds__(256) void gemm_dt_mfma(
    const __hip_bfloat16* __restrict__ A, const __hip_bfloat16* __restrict__ W,
    const float* __restrict__ s, const float* __restrict__ xs,
    float2* __restrict__ dmx) {
    __shared__ __hip_bfloat16 smA[64 * 32];
    __shared__ __hip_bfloat16 smB[64 * 32];
    __shared__ float t0[64][65];
    __shared__ float t1[64][65];
    const int tid = threadIdx.x;
    const int w = tid >> 6, lane = tid & 63;
    const int bm = blockIdx.y * 64, bn = blockIdx.x * 64;
    const int wr = (w >> 1) * 32, wc = (w & 1) * 32;
    const int fr = lane & 15, fq = lane >> 4;
    const int srow = lane >> 2;
    const int scol = (lane & 3) * 8;

    f32x4 acc[2][2];
    #pragma unroll
    for (int i = 0; i < 2; ++i)
        #pragma unroll
        for (int j = 0; j < 2; ++j)
            acc[i][j] = (f32x4){0.f, 0.f, 0.f, 0.f};

    #pragma unroll
    for (int k0 = 0; k0 < 64; k0 += 32) {
        {
            int rr = w * 16;
            gload_lds16(A + (size_t)(bm + rr + srow) * 64 + k0 + scol, &smA[rr * 32]);
            gload_lds16(W + (size_t)(bn + rr + srow) * 64 + k0 + scol, &smB[rr * 32]);
        }
        __syncthreads();
        sh8 af[2], bfr[2];
        #pragma unroll
        for (int i = 0; i < 2; ++i)
            af[i] = *(const sh8*)&smA[(wr + i * 16 + fr) * 32 + fq * 8];
        #pragma unroll
        for (int j = 0; j < 2; ++j)
            bfr[j] = *(const sh8*)&smB[(wc + j * 16 + fr) * 32 + fq * 8];
        #pragma unroll
        for (int i = 0; i < 2; ++i)
            #pragma unroll
            for (int j = 0; j < 2; ++j)
                acc[i][j] = __builtin_amdgcn_mfma_f32_16x16x32_bf16(af[i], bfr[j], acc[i][j], 0, 0, 0);
        __syncthreads();
    }
    #pragma unroll
    for (int i = 0; i < 2; ++i) {
        #pragma unroll
        for (int q = 0; q < 4; ++q) {
            int r = wr + i * 16 + fq * 4 + q;
            float sc = s[bm + r];
            #pragma unroll
            for (int j = 0; j < 2; ++j) {
                int col = wc + j * 16 + fr;
                t0[col][r] = acc[i][j][q] * sc;
            }
        }
    }
    #pragma unroll
    for (int it = 0; it < 16; ++it) {
        int idx = tid + it * 256;
        int rr = idx >> 6, cc = idx & 63;
        t1[cc][rr] = xs[(size_t)(bm + rr) * D_INNER + bn + cc];
    }
    __syncthreads();
    int b = bm >> 10, lbase = bm & 1023;
    #pragma unroll
    for (int it = 0; it < 16; ++it) {
        int idx = tid + it * 256;
        int dd = idx >> 6, ll = idx & 63;
        float dm = t0[dd][ll];
        float xv = t1[dd][ll];
        float dtv = clampf(0.5f * (dm + sqrtf(fmaf(dm, dm, 4.f))) * 0.01f, 0.f, 0.1f);
        size_t dst = ((size_t)(bn + dd) * Bb + b) * Ll + lbase + ll;
        dmx[dst] = make_float2(dm, xv * dtv);
    }
}

// ---------------- chunked parallel scan + C-contraction (4 states/thread, no LDS staging) ----------------
// dmx read directly from global: each wave's chunks touch only its own 2KB slice, so
// the LDS stage + barrier was pure overhead. Unrolled loops let loads hoist ahead of
// the dependent h-chain. LDS now only Ps/Hs/Cin (12.3 KB) -> 8 blocks/CU (wave cap).
#define NCHUNK 64
#define CLEN   16
__global__ __launch_bounds__(256) void scan_chunked(
    const float2* __restrict__ dmx,
    const float* __restrict__ proj,
    const float* __restrict__ base, const float* __restrict__ shifts,
    float* __restrict__ yg) {
    int bid = (blockIdx.x & 7) * 384 + (blockIdx.x >> 3);   // bijective on [0,3072)
    int d = bid >> 1, b = bid & 1;
    int tid = threadIdx.x;
    int chunk = tid >> 2, sub = tid & 3;
    __shared__ float Ps[NCHUNK][16];
    __shared__ float Hs[NCHUNK][16];
    __shared__ float Cin[NCHUNK][16];
    float bs[4], asc[4], h[4], P[4];
    #pragma unroll
    for (int j = 0; j < 4; ++j) {
        int n = sub * 4 + j;
        bs[j]  = base[d * D_STATE + n];
        asc[j] = exp2f(-shifts[d * D_STATE + n]);
        h[j] = 0.f;
        P[j] = 1.f;
    }
    int l0 = chunk * CLEN;
    const float2* dmxR = dmx + (size_t)bid * Ll + l0;
    const float* projR = proj + (size_t)(b * Ll) * PROJ_DIM;
    // pass A: local scan from 0, record (prod a, h_end)
    #pragma unroll
    for (int s = 0; s < CLEN; ++s) {
        float2 dx = dmxR[s];
        f32x4 Bv = *(const f32x4*)&projR[(size_t)(l0 + s) * PROJ_DIM + DT_RANK + sub * 4];
        #pragma unroll
        for (int j = 0; j < 4; ++j) {
            float u = clampf(dx.y * Bv[j], -100.f, 100.f);
            float a = clampf(bs[j] + dx.x, 0.f, 32000.f) * asc[j];
            h[j] = fmaf(a, h[j], u);
            P[j] *= a;
        }
    }
    #pragma unroll
    for (int j = 0; j < 4; ++j) {
        Ps[chunk][sub * 4 + j] = P[j];
        Hs[chunk][sub * 4 + j] = h[j];
    }
    __syncthreads();
    // mid-scan over chunk summaries (serial, 16 threads = 16 states)
    if (tid < 16) {
        float carry = 0.f;
        for (int c = 0; c < NCHUNK; ++c) {
            Cin[c][tid] = carry;
            carry = fmaf(Ps[c][tid], carry, Hs[c][tid]);
        }
    }
    __syncthreads();
    #pragma unroll
    for (int j = 0; j < 4; ++j) h[j] = Cin[chunk][sub * 4 + j];
    // pass C: re-scan with carry-in; y = 4 in-thread fmas + quad butterfly; store raw y
    float* ygr = yg + (size_t)(b * Ll) * D_INNER + d;
    #pragma unroll
    for (int s = 0; s < CLEN; ++s) {
        float2 dx = dmxR[s];
        size_t pr = (size_t)(l0 + s) * PROJ_DIM + DT_RANK + sub * 4;
        f32x4 Bv = *(const f32x4*)&projR[pr];
        f32x4 Cv = *(const f32x4*)&projR[pr + D_STATE];
        float y = 0.f;
        #pragma unroll
        for (int j = 0; j < 4; ++j) {
            float u = clampf(dx.y * Bv[j], -100.f, 100.f);
            float a = clampf(bs[j] + dx.x, 0.f, 32000.f) * asc[j];
            h[j] = fmaf(a, h[j], u);
            float hc = clampf(h[j], -1000.f, 1000.f);
            y = fmaf(hc, Cv[j], y);
        }
        int t;
        t = __builtin_amdgcn_update_dpp(0, __float_as_int(y), 0xB1, 0xF, 0xF, true);
        y += __int_as_float(t);
        t = __builtin_amdgcn_update_dpp(0, __float_as_int(y), 0x4E, 0xF, 0xF, true);
        y += __int_as_float(t);
        if (sub == 0) {
            ygr[(size_t)(l0 + s) * D_INNER] = y;
        }
    }
}

// ---------------- launcher ----------------
extern "C" void kernel_launch(void* const* d_in, const int* in_sizes, int n_in,
                              void* d_out, int out_size, void* d_ws, size_t ws_size,
                              hipStream_t stream) {
    const float* hs    = (const float*)d_in[0];
    const float* gamma = (const float*)d_in[1];
    const float* w_in  = (const float*)d_in[2];
    const float* cw    = (const float*)d_in[3];
    const float* cb    = (const float*)d_in[4];
    const float* w_xp  = (const float*)d_in[5];
    const float* w_dt  = (const float*)d_in[6];
    const float* w_out = (const float*)d_in[7];
    const float* base  = (const float*)d_in[8];
    const float* rg    = (const float*)d_in[9];
    const float* shifts= (const float*)d_in[10];
    float* ws  = (float*)d_ws;
    float* out = (float*)d_out;

    __hip_bfloat16* wqin  = (__hip_bfloat16*)(ws + OFF_WQIN);
    __hip_bfloat16* wqdt  = (__hip_bfloat16*)(ws + OFF_WQDT);
    __hip_bfloat16* wqout = (__hip_bfloat16*)(ws + OFF_WQOUT);
    __hip_bfloat16* xq1   = (__hip_bfloat16*)(ws + OFF_XQ1);
    __hip_bfloat16* xq3   = (__hip_bfloat16*)(ws + OFF_XQ3);
    __hip_bfloat16* xq4   = (__hip_bfloat16*)(ws + OFF_XQ4);
    float2*         dmx   = (float2*)(ws + OFF_DMX);

    // 1. weight scales
    absmean_all<<<1024, 256, 0, stream>>>(w_in, w_xp, w_dt, w_out, ws + OFF_S2);
    absmean_final4<<<1, 256, 0, stream>>>(ws + OFF_S2, ws + OFF_SW);
    // 2. ternary weights
    const int n_tot = N_IN_W + N_XP_W + N_DT_P + N_OUT_W;
    quant_all<<<(n_tot + 255) / 256, 256, 0, stream>>>(
        w_in, w_xp, w_dt, w_out, ws + OFF_SW,
        wqin, ws + OFF_WQXPT, wqdt, wqout);
    // 3. norm + act quant (bf16)
    norm_quant<<<ROWS, 256, 0, stream>>>(hs, gamma, ws + OFF_SW + 0, xq1, ws + OFF_S1);
    // 4. in_proj MFMA GEMM -> xz (<4,2>: 128x64 tile, 768 blocks = 3/CU)
    gemm_mfma<4, 2><<<dim3(XZ_DIM / 64, ROWS / 128), 256, 0, stream>>>(
        xq1, wqin, ws + OFF_S1, ws + OFF_XZ,
        ROWS, XZ_DIM, D_MODEL, nullptr, nullptr);
    // 5-8. FUSED conv + softplus + quant(LDS) + x_proj GEMM + dt-quant (2 rows/block)
    conv_xproj<<<ROWS / CR2, 512, 0, stream>>>(ws + OFF_XZ, cw, cb, ws + OFF_SW,
                                               ws + OFF_WQXPT, ws + OFF_XS,
                                               ws + OFF_PROJ, xq3, ws + OFF_S3);
    // 9+10a. dt_proj MFMA GEMM + fused dtv/xdt/transpose -> dmx (float2)
    gemm_dt_mfma<<<dim3(D_INNER / 64, ROWS / 64), 256, 0, stream>>>(
        xq3, wqdt, ws + OFF_S3, ws + OFF_XS, dmx);
    // 10b. chunked scan -> raw y (4 states/thread, direct-L2 dmx, XCD write swizzle)
    scan_chunked<<<Bb * D_INNER, 256, 0, stream>>>(
        dmx, ws + OFF_PROJ, base, shifts, ws + OFF_YG);
    // 11. gate + quant for out_proj (bf16)
    gate_rowmax_quant_bf16<<<ROWS, 256, 0, stream>>>(ws + OFF_YG, ws + OFF_XZ,
                                                     ws + OFF_SW + 3, xq4, ws + OFF_S4);
    // 12. out_proj MFMA GEMM + residual epilogue -> d_out (<2,1>: 64x32, 768 blocks = 3/CU)
    gemm_mfma<2, 1><<<dim3(D_MODEL / 32, ROWS / 64), 256, 0, stream>>>(
        xq4, wqout, ws + OFF_S4, out,
        ROWS, D_MODEL, D_INNER, hs, rg);
}

// Round 21
// 173.264 us; speedup vs baseline: 1.0570x; 1.0570x over previous
//
#include <hip/hip_runtime.h>
#include <hip/hip_bf16.h>
#include <math.h>

// ---------------- problem constants ----------------
#define D_MODEL 768
#define D_STATE 16
#define DT_RANK 48
#define D_INNER 1536           // 2*D_MODEL
#define XZ_DIM  3072           // 2*D_INNER
#define PROJ_DIM 80            // DT_RANK + 2*D_STATE
#define Bb 2
#define Ll 1024
#define ROWS (Bb*Ll)           // 2048

// ---------------- ws layout (float offsets; bf16 buffers reuse same regions) ----------------
#define OFF_PART   0u                     // (legacy, unused)
#define OFF_SW     256u                   // 4 scalars
#define OFF_WQIN   512u                   // bf16 [3072][768]
#define OFF_WQXPT  (OFF_WQIN  + 2359296u) // f32 [1536][80] (transposed)
#define OFF_WQDT   (OFF_WQXPT + 122880u)  // bf16 [1536][64] (K zero-padded 48->64)
#define OFF_WQOUT  (OFF_WQDT  + 73728u)   // bf16 [768][1536]
#define OFF_XQ1    (OFF_WQOUT + 1179648u) // bf16 [2048][768]
#define OFF_S1     (OFF_XQ1   + 1572864u) // 2048
#define OFF_XZ     (OFF_S1    + 2048u)    // f32 [2048][3072]
#define OFF_XS     (OFF_XZ    + 6291456u) // f32 [2048][1536]
#define OFF_YG     (OFF_XS    + 3145728u) // f32 [2048][1536] (raw y, pre-gate)
#define OFF_S2     (OFF_YG    + 3145728u) // 2048 floats -> absmean partials (1024 used)
#define OFF_PROJ   (OFF_S2    + 2048u)    // f32 [2048][80]
#define OFF_XQ3    (OFF_PROJ  + 163840u)  // bf16 [2048][64] (padded)
#define OFF_S3     (OFF_XQ3   + 98304u)   // 2048
#define OFF_DMX    (OFF_S3    + 2048u)    // float2 [1536*2][1024] = 6291456 floats
#define OFF_XQ4    (OFF_DMX   + 6291456u) // bf16 [2048][1536]
#define OFF_S4     (OFF_XQ4   + 3145728u) // 2048

typedef short sh8 __attribute__((ext_vector_type(8)));
typedef float f32x4 __attribute__((ext_vector_type(4)));

#define N_IN_W  (XZ_DIM * D_MODEL)     // 2359296
#define N_XP_W  (PROJ_DIM * D_INNER)   // 122880
#define N_DT_P  (D_INNER * 64)         // 98304 (padded)
#define N_OUT_W (D_MODEL * D_INNER)    // 1179648

// ---------------- helpers ----------------
__device__ __forceinline__ float blk_sum(float v, float* sm) {
    int tid = threadIdx.x;
    #pragma unroll
    for (int off = 32; off; off >>= 1) v += __shfl_down(v, off);
    __syncthreads();
    if ((tid & 63) == 0) sm[tid >> 6] = v;
    __syncthreads();
    return (sm[0] + sm[1]) + (sm[2] + sm[3]);
}
__device__ __forceinline__ float blk_max(float v, float* sm) {
    int tid = threadIdx.x;
    #pragma unroll
    for (int off = 32; off; off >>= 1) v = fmaxf(v, __shfl_down(v, off));
    __syncthreads();
    if ((tid & 63) == 0) sm[tid >> 6] = v;
    __syncthreads();
    return fmaxf(fmaxf(sm[0], sm[1]), fmaxf(sm[2], sm[3]));
}
__device__ __forceinline__ float clampf(float v, float lo, float hi) {
    return fminf(fmaxf(v, lo), hi);
}
__device__ __forceinline__ void gload_lds16(const __hip_bfloat16* g, __hip_bfloat16* l) {
    __builtin_amdgcn_global_load_lds(
        (const __attribute__((address_space(1))) void*)g,
        (__attribute__((address_space(3))) void*)l, 16, 0, 0);
}

// ---------------- weight absmean: 1024 partial blocks (full occupancy) ----------------
__global__ __launch_bounds__(256) void absmean_all(
    const float* __restrict__ w0, const float* __restrict__ w1,
    const float* __restrict__ w2, const float* __restrict__ w3,
    float* __restrict__ part) {
    __shared__ float sm[4];
    int bid = blockIdx.x;
    const float* w; int n, sub, nb;
    if (bid < 512)      { w = w0; n = N_IN_W;           sub = bid;       nb = 512; }
    else if (bid < 576) { w = w1; n = N_XP_W;           sub = bid - 512; nb = 64;  }
    else if (bid < 640) { w = w2; n = D_INNER*DT_RANK;  sub = bid - 576; nb = 64;  }
    else                { w = w3; n = N_OUT_W;          sub = bid - 640; nb = 384; }
    float sum = 0.f;
    for (int i = sub * 256 + threadIdx.x; i < n; i += nb * 256)
        sum += fabsf(w[i]);
    sum = blk_sum(sum, sm);
    if (threadIdx.x == 0) part[bid] = sum;
}

__global__ __launch_bounds__(256) void absmean_final4(
    const float* __restrict__ part, float* __restrict__ sw) {
    __shared__ float sm[4];
    int tid = threadIdx.x;  // 256 threads
    const int cnt[4] = {512, 64, 64, 384};
    const int off[4] = {0, 512, 576, 640};
    const int ns[4]  = {N_IN_W, N_XP_W, D_INNER*DT_RANK, N_OUT_W};
    #pragma unroll
    for (int m = 0; m < 4; ++m) {
        float v = 0.f;
        for (int i = tid; i < cnt[m]; i += 256) v += part[off[m] + i];
        v = blk_sum(v, sm);
        if (tid == 0) sw[m] = v / (float)ns[m] + 1e-6f;
    }
}

// ---------------- all 4 weight quantizations in one launch ----------------
__global__ void quant_all(const float* __restrict__ w_in, const float* __restrict__ w_xp,
                          const float* __restrict__ w_dt, const float* __restrict__ w_out,
                          const float* __restrict__ sw,
                          __hip_bfloat16* __restrict__ wqin, float* __restrict__ wqxpT,
                          __hip_bfloat16* __restrict__ wqdt, __hip_bfloat16* __restrict__ wqout) {
    int idx = blockIdx.x * 256 + threadIdx.x;
    if (idx < N_IN_W) {
        float v = rintf(clampf(w_in[idx] / sw[0], -1.f, 1.f));
        wqin[idx] = __float2bfloat16(v);
    } else if (idx < N_IN_W + N_XP_W) {
        int i = idx - N_IN_W;
        int j = i / D_INNER, k = i % D_INNER;
        wqxpT[k * PROJ_DIM + j] = rintf(clampf(w_xp[i] / sw[1], -1.f, 1.f));
    } else if (idx < N_IN_W + N_XP_W + N_DT_P) {
        int i = idx - N_IN_W - N_XP_W;
        int r = i >> 6, c = i & 63;
        float v = (c < DT_RANK) ? rintf(clampf(w_dt[r * DT_RANK + c] / sw[2], -1.f, 1.f)) : 0.f;
        wqdt[i] = __float2bfloat16(v);
    } else if (idx < N_IN_W + N_XP_W + N_DT_P + N_OUT_W) {
        int i = idx - N_IN_W - N_XP_W - N_DT_P;
        float v = rintf(clampf(w_out[i] / sw[3], -1.f, 1.f));
        wqout[i] = __float2bfloat16(v);
    }
}

// ---------------- fused center x2 + bitshift-norm + act quant (bf16 out) ----------------
__global__ __launch_bounds__(256) void norm_quant(
    const float* __restrict__ x, const float* __restrict__ gamma,
    const float* __restrict__ swp, __hip_bfloat16* __restrict__ xq, float* __restrict__ s1) {
    int row = blockIdx.x, tid = threadIdx.x;
    const float* xr = x + (size_t)row * D_MODEL;
    __shared__ float sm[4];
    float v0 = xr[tid], v1 = xr[tid + 256], v2 = xr[tid + 512];
    float m1 = blk_sum(v0 + v1 + v2, sm) * (1.f / D_MODEL);
    v0 -= m1; v1 -= m1; v2 -= m1;
    float m2 = blk_sum(v0 + v1 + v2, sm) * (1.f / D_MODEL);
    v0 -= m2; v1 -= m2; v2 -= m2;
    float var = blk_sum(v0 * v0 + v1 * v1 + v2 * v2, sm) * (1.f / D_MODEL);
    float rms = sqrtf(var + 1e-6f);
    float k = fmaxf(rintf(log2f(rms)), 0.f);
    float inv = exp2f(-k);
    float g0 = gamma[tid], g1 = gamma[tid + 256], g2 = gamma[tid + 512];
    float h0 = v0 * inv * g0, h1 = v1 * inv * g1, h2 = v2 * inv * g2;
    float mx = blk_max(fmaxf(fabsf(h0), fmaxf(fabsf(h1), fabsf(h2))), sm);
    float sx = 127.f / (mx + 1e-6f);
    __hip_bfloat16* xo = xq + (size_t)row * D_MODEL;
    xo[tid]       = __float2bfloat16(rintf(clampf(h0 * sx, -128.f, 127.f)));
    xo[tid + 256] = __float2bfloat16(rintf(clampf(h1 * sx, -128.f, 127.f)));
    xo[tid + 512] = __float2bfloat16(rintf(clampf(h2 * sx, -128.f, 127.f)));
    if (tid == 0) s1[row] = swp[0] * (mx + 1e-6f) / 127.f;
}

// ---------------- gate + row-wise |max| + act quant (bf16 out) ----------------
__global__ __launch_bounds__(256) void gate_rowmax_quant_bf16(
    const float* __restrict__ yr, const float* __restrict__ xz,
    const float* __restrict__ swp,
    __hip_bfloat16* __restrict__ xq, float* __restrict__ sout) {
    int row = blockIdx.x, tid = threadIdx.x;
    const float* ir = yr + (size_t)row * D_INNER;
    const float* zr = xz + (size_t)row * XZ_DIM + D_INNER;
    __shared__ float sm[4];
    float v[6];
    #pragma unroll
    for (int k6 = 0; k6 < 6; ++k6) {
        int k = tid + k6 * 256;
        float z = zr[k];
        float g = 0.5f * (z / sqrtf(fmaf(z, z, 1.f)) + 1.f);
        v[k6] = ir[k] * g;
    }
    float mx = 0.f;
    #pragma unroll
    for (int k6 = 0; k6 < 6; ++k6) mx = fmaxf(mx, fabsf(v[k6]));
    mx = blk_max(mx, sm);
    float sx = 127.f / (mx + 1e-6f);
    #pragma unroll
    for (int k6 = 0; k6 < 6; ++k6) {
        int k = tid + k6 * 256;
        xq[(size_t)row * D_INNER + k] = __float2bfloat16(rintf(clampf(v[k6] * sx, -128.f, 127.f)));
    }
    if (tid == 0) sout[row] = swp[0] * (mx + 1e-6f) / 127.f;
}

// ---------------- MFMA bf16 GEMM: C[M,N] = (A[M,K] @ W[N,K]^T) * s[row] (+resid) ----------------
template<int MF, int NF>
__global__ __launch_bounds__(256) void gemm_mfma(
    const __hip_bfloat16* __restrict__ A, const __hip_bfloat16* __restrict__ W,
    const float* __restrict__ s, float* __restrict__ C,
    int M, int N, int K,
    const float* __restrict__ resid, const float* __restrict__ rg) {
    constexpr int BM = MF * 32, BN = NF * 32;
    __shared__ __hip_bfloat16 smA[BM * 32];
    __shared__ __hip_bfloat16 smB[BN * 32];
    const int tid = threadIdx.x;
    const int w = tid >> 6, lane = tid & 63;
    const int bm = blockIdx.y * BM, bn = blockIdx.x * BN;
    const int wr = (w >> 1) * (MF * 16), wc = (w & 1) * (NF * 16);
    const int fr = lane & 15, fq = lane >> 4;
    const int srow = lane >> 2;
    const int scol = (lane & 3) * 8;

    f32x4 acc[MF][NF];
    #pragma unroll
    for (int i = 0; i < MF; ++i)
        #pragma unroll
        for (int j = 0; j < NF; ++j)
            acc[i][j] = (f32x4){0.f, 0.f, 0.f, 0.f};

    for (int k0 = 0; k0 < K; k0 += 32) {
        #pragma unroll
        for (int q = 0; q < BM / 64; ++q) {
            int rr = (w * (BM / 64) + q) * 16;
            gload_lds16(A + (size_t)(bm + rr + srow) * K + k0 + scol, &smA[rr * 32]);
        }
        if (w < (BN / 16)) {
            int rr = w * 16;
            gload_lds16(W + (size_t)(bn + rr + srow) * K + k0 + scol, &smB[rr * 32]);
        }
        __syncthreads();
        sh8 af[MF], bfr[NF];
        #pragma unroll
        for (int i = 0; i < MF; ++i)
            af[i] = *(const sh8*)&smA[(wr + i * 16 + fr) * 32 + fq * 8];
        #pragma unroll
        for (int j = 0; j < NF; ++j)
            bfr[j] = *(const sh8*)&smB[(wc + j * 16 + fr) * 32 + fq * 8];
        #pragma unroll
        for (int i = 0; i < MF; ++i)
            #pragma unroll
            for (int j = 0; j < NF; ++j)
                acc[i][j] = __builtin_amdgcn_mfma_f32_16x16x32_bf16(af[i], bfr[j], acc[i][j], 0, 0, 0);
        __syncthreads();
    }
    const float rgv = resid ? rg[0] : 0.f;
    #pragma unroll
    for (int i = 0; i < MF; ++i) {
        #pragma unroll
        for (int q = 0; q < 4; ++q) {
            int r = bm + wr + i * 16 + fq * 4 + q;
            float sc = s[r];
            #pragma unroll
            for (int j = 0; j < NF; ++j) {
                int col = bn + wc + j * 16 + fr;
                float v = acc[i][j][q] * sc;
                size_t o = (size_t)r * N + col;
                if (resid) v = resid[o] + v * rgv;
                C[o] = v;
            }
        }
    }
}

// ---------------- FUSED (2 rows/block): conv+softplus+quant(LDS) + x_proj GEMM + dt-quant ----------------
#define CR2 2
__global__ __launch_bounds__(512) void conv_xproj(
    const float* __restrict__ xz, const float* __restrict__ cw, const float* __restrict__ cb,
    const float* __restrict__ swp,            // sw[4]; uses [1] for x_proj, [2] for dt
    const float* __restrict__ wT,             // wqxpT f32 [1536][80]
    float* __restrict__ xs,
    float* __restrict__ proj, __hip_bfloat16* __restrict__ xq3, float* __restrict__ s3) {
    int row0 = blockIdx.x * CR2;
    int tid = threadIdx.x;
    int w = tid >> 6, lane = tid & 63;
    int r = w >> 2, q = w & 3;
    __shared__ float sm8[8];
    __shared__ float a[CR2][D_INNER];           // 12.3 KB
    __shared__ float psum[16][CR2][PROJ_DIM];   // 10.2 KB
    __shared__ float pvL[CR2][PROJ_DIM];        // 0.6 KB
    __shared__ float s2s[CR2];

    // phase 1: conv + softplus (4 waves per row, 384 channels each)
    int row = row0 + r;
    int b = row >> 10, l = row & 1023;
    float v[6];
    float mx = 0.f;
    #pragma unroll
    for (int k = 0; k < 6; ++k) {
        int c = q * 384 + lane + k * 64;
        float acc = cb[c];
        #pragma unroll
        for (int t = 0; t < 4; ++t) {
            int tt = l - 3 + t;
            if (tt >= 0)
                acc = fmaf(cw[c * 4 + t], xz[(size_t)(b * Ll + tt) * XZ_DIM + c], acc);
        }
        acc = clampf(acc, -50.f, 50.f);
        v[k] = 0.5f * (acc + sqrtf(fmaf(acc, acc, 4.f)));
        mx = fmaxf(mx, fabsf(v[k]));
    }
    #pragma unroll
    for (int off = 32; off; off >>= 1) mx = fmaxf(mx, __shfl_xor(mx, off));
    if (lane == 0) sm8[w] = mx;
    __syncthreads();
    mx = fmaxf(fmaxf(sm8[r * 4 + 0], sm8[r * 4 + 1]), fmaxf(sm8[r * 4 + 2], sm8[r * 4 + 3]));
    float sx = 127.f / (mx + 1e-6f);
    #pragma unroll
    for (int k = 0; k < 6; ++k) {
        int c = q * 384 + lane + k * 64;
        xs[(size_t)row * D_INNER + c] = v[k];
        a[r][c] = rintf(clampf(v[k] * sx, -128.f, 127.f));
    }
    if (lane == 0 && q == 0) s2s[r] = swp[1] * (mx + 1e-6f) / 127.f;
    __syncthreads();

    // phase 2: 1280 tasks = 16 K-chunks x 80 cols; both rows per wT load
    for (int task = tid; task < 16 * PROJ_DIM; task += 512) {
        int h = task / PROJ_DIM;
        int col = task - h * PROJ_DIM;
        int k0 = h * 96;
        float a0 = 0.f, a1 = 0.f;
        for (int k = k0; k < k0 + 96; ++k) {
            float wv = wT[k * PROJ_DIM + col];
            a0 = fmaf(a[0][k], wv, a0);
            a1 = fmaf(a[1][k], wv, a1);
        }
        psum[h][0][col] = a0;
        psum[h][1][col] = a1;
    }
    __syncthreads();
    for (int o = tid; o < CR2 * PROJ_DIM; o += 512) {
        int rr = o / PROJ_DIM, col = o - rr * PROJ_DIM;
        float p0 = (psum[0][rr][col] + psum[1][rr][col]) + (psum[2][rr][col] + psum[3][rr][col]);
        float p1 = (psum[4][rr][col] + psum[5][rr][col]) + (psum[6][rr][col] + psum[7][rr][col]);
        float p2 = (psum[8][rr][col] + psum[9][rr][col]) + (psum[10][rr][col] + psum[11][rr][col]);
        float p3 = (psum[12][rr][col] + psum[13][rr][col]) + (psum[14][rr][col] + psum[15][rr][col]);
        float pv = ((p0 + p1) + (p2 + p3)) * s2s[rr];
        proj[(size_t)(row0 + rr) * PROJ_DIM + col] = pv;
        pvL[rr][col] = pv;
    }
    __syncthreads();
    // dt-quant: waves 0..1 handle rows 0..1
    if (w < CR2) {
        float pvv = (lane < DT_RANK) ? pvL[w][lane] : 0.f;
        float av = fabsf(pvv);
        #pragma unroll
        for (int off = 32; off; off >>= 1) av = fmaxf(av, __shfl_xor(av, off));
        float sxd = 127.f / (av + 1e-6f);
        float qv = (lane < DT_RANK) ? rintf(clampf(pvv * sxd, -128.f, 127.f)) : 0.f;
        xq3[(size_t)(row0 + w) * 64 + lane] = __float2bfloat16(qv);
        if (lane == 0) s3[row0 + w] = swp[2] * (av + 1e-6f) / 127.f;
    }
}

// ---------------- dt_proj MFMA GEMM (K=64 padded) + fused dtv/xdt + transpose -> float2 dmx ----------------
__global__ __launch_bounds__(256) void gemm_dt_mfma(
    const __hip_bfloat16* __restrict__ A, const __hip_bfloat16* __restrict__ W,
    const float* __restrict__ s, const float* __restrict__ xs,
    float2* __restrict__ dmx) {
    __shared__ __hip_bfloat16 smA[64 * 32];
    __shared__ __hip_bfloat16 smB[64 * 32];
    __shared__ float t0[64][65];
    __shared__ float t1[64][65];
    const int tid = threadIdx.x;
    const int w = tid >> 6, lane = tid & 63;
    const int bm = blockIdx.y * 64, bn = blockIdx.x * 64;
    const int wr = (w >> 1) * 32, wc = (w & 1) * 32;
    const int fr = lane & 15, fq = lane >> 4;
    const int srow = lane >> 2;
    const int scol = (lane & 3) * 8;

    f32x4 acc[2][2];
    #pragma unroll
    for (int i = 0; i < 2; ++i)
        #pragma unroll
        for (int j = 0; j < 2; ++j)
            acc[i][j] = (f32x4){0.f, 0.f, 0.f, 0.f};

    #pragma unroll
    for (int k0 = 0; k0 < 64; k0 += 32) {
        {
            int rr = w * 16;
            gload_lds16(A + (size_t)(bm + rr + srow) * 64 + k0 + scol, &smA[rr * 32]);
            gload_lds16(W + (size_t)(bn + rr + srow) * 64 + k0 + scol, &smB[rr * 32]);
        }
        __syncthreads();
        sh8 af[2], bfr[2];
        #pragma unroll
        for (int i = 0; i < 2; ++i)
            af[i] = *(const sh8*)&smA[(wr + i * 16 + fr) * 32 + fq * 8];
        #pragma unroll
        for (int j = 0; j < 2; ++j)
            bfr[j] = *(const sh8*)&smB[(wc + j * 16 + fr) * 32 + fq * 8];
        #pragma unroll
        for (int i = 0; i < 2; ++i)
            #pragma unroll
            for (int j = 0; j < 2; ++j)
                acc[i][j] = __builtin_amdgcn_mfma_f32_16x16x32_bf16(af[i], bfr[j], acc[i][j], 0, 0, 0);
        __syncthreads();
    }
    #pragma unroll
    for (int i = 0; i < 2; ++i) {
        #pragma unroll
        for (int q = 0; q < 4; ++q) {
            int r = wr + i * 16 + fq * 4 + q;
            float sc = s[bm + r];
            #pragma unroll
            for (int j = 0; j < 2; ++j) {
                int col = wc + j * 16 + fr;
                t0[col][r] = acc[i][j][q] * sc;
            }
        }
    }
    #pragma unroll
    for (int it = 0; it < 16; ++it) {
        int idx = tid + it * 256;
        int rr = idx >> 6, cc = idx & 63;
        t1[cc][rr] = xs[(size_t)(bm + rr) * D_INNER + bn + cc];
    }
    __syncthreads();
    int b = bm >> 10, lbase = bm & 1023;
    #pragma unroll
    for (int it = 0; it < 16; ++it) {
        int idx = tid + it * 256;
        int dd = idx >> 6, ll = idx & 63;
        float dm = t0[dd][ll];
        float xv = t1[dd][ll];
        float dtv = clampf(0.5f * (dm + sqrtf(fmaf(dm, dm, 4.f))) * 0.01f, 0.f, 0.1f);
        size_t dst = ((size_t)(bn + dd) * Bb + b) * Ll + lbase + ll;
        dmx[dst] = make_float2(dm, xv * dtv);
    }
}

// ---------------- chunked parallel scan + C-contraction (R19-proven form) ----------------
// 4 states/thread, LDS-staged dmx (padded), XCD write-locality bid swizzle.
#define NCHUNK 64
#define CLEN   16
#define PADIDX(i) ((i) + ((i) >> 5))
__global__ __launch_bounds__(256) void scan_chunked(
    const float2* __restrict__ dmx,
    const float* __restrict__ proj,
    const float* __restrict__ base, const float* __restrict__ shifts,
    float* __restrict__ yg) {
    int bid = (blockIdx.x & 7) * 384 + (blockIdx.x >> 3);   // bijective on [0,3072)
    int d = bid >> 1, b = bid & 1;
    int tid = threadIdx.x;
    int chunk = tid >> 2, sub = tid & 3;
    __shared__ float2 dmxL[Ll + Ll / 32];
    __shared__ float Ps[NCHUNK][16];
    __shared__ float Hs[NCHUNK][16];
    __shared__ float Cin[NCHUNK][16];
    size_t tbase = (size_t)bid * Ll;
    for (int i = tid; i < Ll; i += 256)
        dmxL[PADIDX(i)] = dmx[tbase + i];
    float bs[4], asc[4], h[4], P[4];
    #pragma unroll
    for (int j = 0; j < 4; ++j) {
        int n = sub * 4 + j;
        bs[j]  = base[d * D_STATE + n];
        asc[j] = exp2f(-shifts[d * D_STATE + n]);
        h[j] = 0.f;
        P[j] = 1.f;
    }
    __syncthreads();
    int l0 = chunk * CLEN;
    int pbase = PADIDX(l0);        // contiguous within 16-chunk (no pad crossing)
    const float* projR = proj + (size_t)(b * Ll) * PROJ_DIM;
    // pass A: local scan from 0, record (prod a, h_end)
    for (int s = 0; s < CLEN; ++s) {
        float2 dx = dmxL[pbase + s];
        f32x4 Bv = *(const f32x4*)&projR[(size_t)(l0 + s) * PROJ_DIM + DT_RANK + sub * 4];
        #pragma unroll
        for (int j = 0; j < 4; ++j) {
            float u = clampf(dx.y * Bv[j], -100.f, 100.f);
            float a = clampf(bs[j] + dx.x, 0.f, 32000.f) * asc[j];
            h[j] = fmaf(a, h[j], u);
            P[j] *= a;
        }
    }
    #pragma unroll
    for (int j = 0; j < 4; ++j) {
        Ps[chunk][sub * 4 + j] = P[j];
        Hs[chunk][sub * 4 + j] = h[j];
    }
    __syncthreads();
    // mid-scan over chunk summaries (serial, 16 threads = 16 states)
    if (tid < 16) {
        float carry = 0.f;
        for (int c = 0; c < NCHUNK; ++c) {
            Cin[c][tid] = carry;
            carry = fmaf(Ps[c][tid], carry, Hs[c][tid]);
        }
    }
    __syncthreads();
    #pragma unroll
    for (int j = 0; j < 4; ++j) h[j] = Cin[chunk][sub * 4 + j];
    // pass C: re-scan with carry-in; y = 4 in-thread fmas + quad butterfly; store raw y
    float* ygr = yg + (size_t)(b * Ll) * D_INNER + d;
    for (int s = 0; s < CLEN; ++s) {
        float2 dx = dmxL[pbase + s];
        size_t pr = (size_t)(l0 + s) * PROJ_DIM + DT_RANK + sub * 4;
        f32x4 Bv = *(const f32x4*)&projR[pr];
        f32x4 Cv = *(const f32x4*)&projR[pr + D_STATE];
        float y = 0.f;
        #pragma unroll
        for (int j = 0; j < 4; ++j) {
            float u = clampf(dx.y * Bv[j], -100.f, 100.f);
            float a = clampf(bs[j] + dx.x, 0.f, 32000.f) * asc[j];
            h[j] = fmaf(a, h[j], u);
            float hc = clampf(h[j], -1000.f, 1000.f);
            y = fmaf(hc, Cv[j], y);
        }
        int t;
        t = __builtin_amdgcn_update_dpp(0, __float_as_int(y), 0xB1, 0xF, 0xF, true);
        y += __int_as_float(t);
        t = __builtin_amdgcn_update_dpp(0, __float_as_int(y), 0x4E, 0xF, 0xF, true);
        y += __int_as_float(t);
        if (sub == 0) {
            ygr[(size_t)(l0 + s) * D_INNER] = y;
        }
    }
}

// ---------------- launcher ----------------
extern "C" void kernel_launch(void* const* d_in, const int* in_sizes, int n_in,
                              void* d_out, int out_size, void* d_ws, size_t ws_size,
                              hipStream_t stream) {
    const float* hs    = (const float*)d_in[0];
    const float* gamma = (const float*)d_in[1];
    const float* w_in  = (const float*)d_in[2];
    const float* cw    = (const float*)d_in[3];
    const float* cb    = (const float*)d_in[4];
    const float* w_xp  = (const float*)d_in[5];
    const float* w_dt  = (const float*)d_in[6];
    const float* w_out = (const float*)d_in[7];
    const float* base  = (const float*)d_in[8];
    const float* rg    = (const float*)d_in[9];
    const float* shifts= (const float*)d_in[10];
    float* ws  = (float*)d_ws;
    float* out = (float*)d_out;

    __hip_bfloat16* wqin  = (__hip_bfloat16*)(ws + OFF_WQIN);
    __hip_bfloat16* wqdt  = (__hip_bfloat16*)(ws + OFF_WQDT);
    __hip_bfloat16* wqout = (__hip_bfloat16*)(ws + OFF_WQOUT);
    __hip_bfloat16* xq1   = (__hip_bfloat16*)(ws + OFF_XQ1);
    __hip_bfloat16* xq3   = (__hip_bfloat16*)(ws + OFF_XQ3);
    __hip_bfloat16* xq4   = (__hip_bfloat16*)(ws + OFF_XQ4);
    float2*         dmx   = (float2*)(ws + OFF_DMX);

    // 1. weight scales
    absmean_all<<<1024, 256, 0, stream>>>(w_in, w_xp, w_dt, w_out, ws + OFF_S2);
    absmean_final4<<<1, 256, 0, stream>>>(ws + OFF_S2, ws + OFF_SW);
    // 2. ternary weights
    const int n_tot = N_IN_W + N_XP_W + N_DT_P + N_OUT_W;
    quant_all<<<(n_tot + 255) / 256, 256, 0, stream>>>(
        w_in, w_xp, w_dt, w_out, ws + OFF_SW,
        wqin, ws + OFF_WQXPT, wqdt, wqout);
    // 3. norm + act quant (bf16)
    norm_quant<<<ROWS, 256, 0, stream>>>(hs, gamma, ws + OFF_SW + 0, xq1, ws + OFF_S1);
    // 4. in_proj MFMA GEMM -> xz (<4,2>: 128x64 tile, 768 blocks = 3/CU)
    gemm_mfma<4, 2><<<dim3(XZ_DIM / 64, ROWS / 128), 256, 0, stream>>>(
        xq1, wqin, ws + OFF_S1, ws + OFF_XZ,
        ROWS, XZ_DIM, D_MODEL, nullptr, nullptr);
    // 5-8. FUSED conv + softplus + quant(LDS) + x_proj GEMM + dt-quant (2 rows/block)
    conv_xproj<<<ROWS / CR2, 512, 0, stream>>>(ws + OFF_XZ, cw, cb, ws + OFF_SW,
                                               ws + OFF_WQXPT, ws + OFF_XS,
                                               ws + OFF_PROJ, xq3, ws + OFF_S3);
    // 9+10a. dt_proj MFMA GEMM + fused dtv/xdt/transpose -> dmx (float2)
    gemm_dt_mfma<<<dim3(D_INNER / 64, ROWS / 64), 256, 0, stream>>>(
        xq3, wqdt, ws + OFF_S3, ws + OFF_XS, dmx);
    // 10b. chunked scan -> raw y (R19 form: LDS-staged, 4 states/thread, XCD swizzle)
    scan_chunked<<<Bb * D_INNER, 256, 0, stream>>>(
        dmx, ws + OFF_PROJ, base, shifts, ws + OFF_YG);
    // 11. gate + quant for out_proj (bf16)
    gate_rowmax_quant_bf16<<<ROWS, 256, 0, stream>>>(ws + OFF_YG, ws + OFF_XZ,
                                                     ws + OFF_SW + 3, xq4, ws + OFF_S4);
    // 12. out_proj MFMA GEMM + residual epilogue -> d_out (<2,1>: 64x32, 768 blocks = 3/CU)
    gemm_mfma<2, 1><<<dim3(D_MODEL / 32, ROWS / 64), 256, 0, stream>>>(
        xq4, wqout, ws + OFF_S4, out,
        ROWS, D_MODEL, D_INNER, hs, rg);
}